// Round 6
// baseline (367.315 us; speedup 1.0000x reference)
//
#include <hip/hip_runtime.h>
#include <hip/hip_fp16.h>

#define NQ 20

__device__ __forceinline__ float bcast_first(float x) {
    return __int_as_float(__builtin_amdgcn_readfirstlane(__float_as_int(x)));
}

// RX butterfly, symmetric form: new = C*mine + SV*(partner.im, -partner.re)
__device__ __forceinline__ void bfly(float C, float SV, float2& a, float2& b) {
    float2 na = make_float2(C * a.x + SV * b.y, C * a.y - SV * b.x);
    float2 nb = make_float2(C * b.x + SV * a.y, C * b.y - SV * a.x);
    a = na; b = nb;
}

// vectorized over two complex packed in float4 (same rotation both halves)
__device__ __forceinline__ void bfly4(float C, float SV, float4& a, float4& b) {
    float4 na = make_float4(C*a.x + SV*b.y, C*a.y - SV*b.x, C*a.z + SV*b.w, C*a.w - SV*b.z);
    float4 nb = make_float4(C*b.x + SV*a.y, C*b.y - SV*a.x, C*b.z + SV*a.w, C*b.w - SV*a.z);
    a = na; b = nb;
}

__device__ __forceinline__ unsigned int pack_h2(float re, float im) {
    __half2 h = __floats2half2_rn(re, im);
    return *(unsigned int*)&h;
}
__device__ __forceinline__ float2 unpack_h2(unsigned int u) {
    return __half22float2(*(__half2*)&u);
}

// row-internal swizzle (2048-uint rows): XOR uint-index bits 2..4 with bits 7..9
__device__ __forceinline__ int swz1(int l) { return l ^ (((l >> 7) & 7) << 2); }

// ---------------------------------------------------------------------------
// Trig table: cos/sin of thetas/2 for all B*NQ angles, computed once.
// ---------------------------------------------------------------------------
__global__ void rx_trig(const float* __restrict__ thetas, float2* __restrict__ tab) {
    int i = threadIdx.x;
    if (i < 16 * NQ) {
        float th = 0.5f * thetas[i];
        tab[i] = make_float2(cosf(th), sinf(th));
    }
}

// ---------------------------------------------------------------------------
// rx_hi: HIGH 9 qubits (state bits 11..19 = "h"). Block (b, lb) owns lows
// [lb*32, lb*32+32) x all 512 h. Reads phi in 128B full-line segments
// (the only strided stream left in the pipeline); writes its fp16 tile
// CONTIGUOUSLY (64 KB) to ws in tile-major layout:
//   inter[tile = b*64+lb][h=0..511][low j=0..31]  (uint = half2 cpx)
// LDS: linear uint[512][32] (row-wise accesses only -> no swizzle needed).
// ---------------------------------------------------------------------------
__global__ __launch_bounds__(512, 4) void rx_hi(
        const float* __restrict__ phi, const float2* __restrict__ tab,
        unsigned int* __restrict__ inter) {
    __shared__ unsigned int T[512 * 32];            // 64 KiB
    const int tid = threadIdx.x;
    const int b  = blockIdx.x >> 6;
    const int lb = blockIdx.x & 63;
    const float* ph = phi + ((size_t)b << NQ) + (lb << 5);
    unsigned int* tp = inter + ((size_t)blockIdx.x << 14);  // 16384 uints/tile

    // h-bit i <-> qubit 8-i
    float c[9], sv[9];
#pragma unroll
    for (int i = 0; i < 9; ++i) {
        float2 t = tab[b * NQ + (8 - i)];
        c[i]  = bcast_first(t.x);
        sv[i] = bcast_first(t.y);
    }

    // Load: 512 rows x 32 floats (128 B = one full line per row-segment)
#pragma unroll
    for (int i = 0; i < 8; ++i) {
        int f = (i << 9) | tid;                     // [0, 4096)
        int h = f >> 3, q = f & 7;
        float4 t = *(const float4*)(ph + h * 2048 + (q << 2));
        uint4 pk;
        pk.x = pack_h2(t.x, 0.f);
        pk.y = pack_h2(t.y, 0.f);
        pk.z = pack_h2(t.z, 0.f);
        pk.w = pack_h2(t.w, 0.f);
        *(uint4*)&T[(h << 5) + (q << 2)] = pk;
    }
    __syncthreads();

    // Stage A: h bits 0..4 in regs. thread (hg, ll): h = hg*32 + r, col ll.
    {
        const int hg = tid >> 5, ll = tid & 31;
        float2 v[32];
#pragma unroll
        for (int r = 0; r < 32; ++r)
            v[r] = unpack_h2(T[((hg << 5) + r) * 32 + ll]);
#pragma unroll
        for (int t = 0; t < 5; ++t) {
            const float C = c[t], SV = sv[t];
            const int m = 1 << t;
#pragma unroll
            for (int r = 0; r < 32; ++r)
                if (!(r & m)) bfly(C, SV, v[r], v[r | m]);
        }
#pragma unroll
        for (int r = 0; r < 32; ++r)
            T[((hg << 5) + r) * 32 + ll] = pack_h2(v[r].x, v[r].y);
    }
    __syncthreads();

    // Stage B: h bits 5..8 in regs. thread (u, llp): h = u + 32*r2,
    // lows (2llp, 2llp+1). Stores straight to the tile: 512B/instr contiguous.
    {
        const int u = tid >> 4, llp = tid & 15;
        float4 w[16];
#pragma unroll
        for (int r2 = 0; r2 < 16; ++r2) {
            uint2 t2 = *(uint2*)&T[((u + (r2 << 5)) << 5) + (llp << 1)];
            float2 a = unpack_h2(t2.x), bb = unpack_h2(t2.y);
            w[r2] = make_float4(a.x, a.y, bb.x, bb.y);
        }
#pragma unroll
        for (int t = 0; t < 4; ++t) {
            const float C = c[5 + t], SV = sv[5 + t];
            const int m = 1 << t;
#pragma unroll
            for (int r2 = 0; r2 < 16; ++r2)
                if (!(r2 & m)) bfly4(C, SV, w[r2], w[r2 | m]);
        }
#pragma unroll
        for (int r2 = 0; r2 < 16; ++r2) {
            uint2 pk;
            pk.x = pack_h2(w[r2].x, w[r2].y);
            pk.y = pack_h2(w[r2].z, w[r2].w);
            *(uint2*)(tp + ((u + (r2 << 5)) << 5) + (llp << 1)) = pk;
        }
    }
}

// ---------------------------------------------------------------------------
// rx_lo: LOW 11 qubits (state bits 0..10). Block (b, h0) owns 8 h-rows x
// 2048 lows (64 KiB LDS as fp16). Reads 1KB-contiguous segments from the
// tile-major intermediate; each wave owns ONE 2048-cpx row -> all exchanges
// are wave-local (no barriers in compute). Writes out in 1KB-contiguous
// float4 streams (16 KB per row).
// ---------------------------------------------------------------------------
__global__ __launch_bounds__(512, 4) void rx_lo(
        const float2* __restrict__ tab, const unsigned int* __restrict__ inter,
        float2* __restrict__ out) {
    __shared__ unsigned int T[8 * 2048];            // 64 KiB
    const int tid = threadIdx.x;
    const int b   = blockIdx.x >> 6;
    const int h0  = (blockIdx.x & 63) << 3;
    float2* op = out + ((size_t)b << NQ) + ((size_t)h0 << 11);

    // low-bit beta <-> qubit 19-beta
    float c[11], sv[11];
#pragma unroll
    for (int beta = 0; beta < 11; ++beta) {
        float2 t = tab[b * NQ + (NQ - 1 - beta)];
        c[beta]  = bcast_first(t.x);
        sv[beta] = bcast_first(t.y);
    }

    // Load: per tile lb, rows h0..h0+8 = 1 KB contiguous. Per wave: one LDS
    // row, contiguous b128 writes (swz1 block-permutes uint4s: conflict-free).
#pragma unroll
    for (int i = 0; i < 8; ++i) {
        int f = (i << 9) | tid;                     // [0, 4096) uint4s
        int hh = f >> 9, rp = f & 511;              // row, uint4-within-row
        int lb = rp >> 3, q = rp & 7;
        uint4 t = *(const uint4*)(inter + (((size_t)(b << 6) + lb) << 14)
                                  + ((h0 + hh) << 5) + (q << 2));
        *(uint4*)&T[(hh << 11) + swz1(rp << 2)] = t;
    }
    __syncthreads();

    // Compute: wave = one row. Same proven structure as pass1 (stage1 bits
    // {0,1,8,9,10}, LDS exchange, stage2 bits {2..6}, bit7 via shfl_xor 4).
    const int hh = tid >> 6, lane = tid & 63;
    unsigned int* R = &T[hh << 11];

    float2 v[32];
#pragma unroll
    for (int k4 = 0; k4 < 8; ++k4) {
        uint4 tq = *(uint4*)&R[swz1((k4 << 8) + (lane << 2))];
        v[k4 * 4 + 0] = unpack_h2(tq.x);
        v[k4 * 4 + 1] = unpack_h2(tq.y);
        v[k4 * 4 + 2] = unpack_h2(tq.z);
        v[k4 * 4 + 3] = unpack_h2(tq.w);
    }

    const int regbit1[5]  = {0, 1, 8, 9, 10};
    const int regmask1[5] = {1, 2, 4, 8, 16};
#pragma unroll
    for (int t = 0; t < 5; ++t) {
        const float C = c[regbit1[t]], SV = sv[regbit1[t]];
        const int m = regmask1[t];
#pragma unroll
        for (int r = 0; r < 32; ++r)
            if (!(r & m)) bfly(C, SV, v[r], v[r | m]);
    }

    // exchange 1 (wave-local; compiler orders via lgkmcnt on aliasing ptr)
#pragma unroll
    for (int k4 = 0; k4 < 8; ++k4) {
        uint4 pk;
        pk.x = pack_h2(v[k4*4+0].x, v[k4*4+0].y);
        pk.y = pack_h2(v[k4*4+1].x, v[k4*4+1].y);
        pk.z = pack_h2(v[k4*4+2].x, v[k4*4+2].y);
        pk.w = pack_h2(v[k4*4+3].x, v[k4*4+3].y);
        *(uint4*)&R[swz1((k4 << 8) + (lane << 2))] = pk;
    }

    const int g = lane >> 2, lam = lane & 3;
#pragma unroll
    for (int r = 0; r < 32; ++r)
        v[r] = unpack_h2(R[swz1((g << 7) | (r << 2) | lam)]);

#pragma unroll
    for (int t = 0; t < 5; ++t) {
        const float C = c[2 + t], SV = sv[2 + t];
        const int m = 1 << t;
#pragma unroll
        for (int r = 0; r < 32; ++r)
            if (!(r & m)) bfly(C, SV, v[r], v[r | m]);
    }

    // bit 7 = lane bit 2 -> partner lane^4, symmetric form
    {
        const float C = c[7], SV = sv[7];
#pragma unroll
        for (int r = 0; r < 32; ++r) {
            float px = __shfl_xor(v[r].x, 4, 64);
            float py = __shfl_xor(v[r].y, 4, 64);
            v[r] = make_float2(C * v[r].x + SV * py, C * v[r].y - SV * px);
        }
    }

    // pack back (same addrs we read)
#pragma unroll
    for (int r = 0; r < 32; ++r)
        R[swz1((g << 7) | (r << 2) | lam)] = pack_h2(v[r].x, v[r].y);

    // gather + store: 2 cpx/lane -> float4, 1 KB contiguous per instruction
#pragma unroll
    for (int k = 0; k < 16; ++k) {
        int j0 = (k << 7) | (lane << 1);
        uint2 t2 = *(uint2*)&R[swz1(j0)];
        float2 a = unpack_h2(t2.x), bb = unpack_h2(t2.y);
        *(float4*)(op + ((size_t)hh << 11) + j0) = make_float4(a.x, a.y, bb.x, bb.y);
    }
}

// ---------------------------------------------------------------------------
// Fallback fp32 path (proven round-0 kernels, inline trig, no ws needed).
// ---------------------------------------------------------------------------
__global__ __launch_bounds__(64) void rx_pass1(
        const float* __restrict__ phi, const float* __restrict__ thetas,
        float2* __restrict__ out) {
    __shared__ float2 lds[2048];
    const int lane = threadIdx.x;
    const int W = blockIdx.x;
    const int b = W >> 9;
    const int base = (W & 511) << 11;
    const float* ph = phi + ((size_t)b << NQ) + base;
    float2* opp = out + ((size_t)b << NQ) + base;

    float c[11], sv[11];
#pragma unroll
    for (int beta = 0; beta < 11; ++beta) {
        float th = 0.5f * thetas[b * NQ + (NQ - 1 - beta)];
        c[beta]  = bcast_first(cosf(th));
        sv[beta] = bcast_first(sinf(th));
    }

    float2 v[32];
#pragma unroll
    for (int k4 = 0; k4 < 8; ++k4) {
        float4 t = *(const float4*)(ph + (k4 << 8) + (lane << 2));
        v[k4 * 4 + 0] = make_float2(t.x, 0.f);
        v[k4 * 4 + 1] = make_float2(t.y, 0.f);
        v[k4 * 4 + 2] = make_float2(t.z, 0.f);
        v[k4 * 4 + 3] = make_float2(t.w, 0.f);
    }

    const int regbit1[5]  = {0, 1, 8, 9, 10};
    const int regmask1[5] = {1, 2, 4, 8, 16};
#pragma unroll
    for (int t = 0; t < 5; ++t) {
        const float C = c[regbit1[t]], SV = sv[regbit1[t]];
        const int m = regmask1[t];
#pragma unroll
        for (int r = 0; r < 32; ++r)
            if (!(r & m)) bfly(C, SV, v[r], v[r | m]);
    }

#pragma unroll
    for (int k4 = 0; k4 < 8; ++k4) {
        int s0 = swz1((k4 << 8) + (lane << 2));
        *(float4*)&lds[s0]     = make_float4(v[k4*4+0].x, v[k4*4+0].y, v[k4*4+1].x, v[k4*4+1].y);
        *(float4*)&lds[s0 + 2] = make_float4(v[k4*4+2].x, v[k4*4+2].y, v[k4*4+3].x, v[k4*4+3].y);
    }
    __syncthreads();

    {
        const int g = lane >> 2, lam = lane & 3;
        float2 w2[32];
#pragma unroll
        for (int r = 0; r < 32; ++r)
            w2[r] = lds[swz1((g << 7) | (r << 2) | lam)];
#pragma unroll
        for (int t = 0; t < 5; ++t) {
            const float C = c[2 + t], SV = sv[2 + t];
            const int m = 1 << t;
#pragma unroll
            for (int r = 0; r < 32; ++r)
                if (!(r & m)) bfly(C, SV, w2[r], w2[r | m]);
        }
#pragma unroll
        for (int r = 0; r < 32; ++r)
            lds[swz1((g << 7) | (r << 2) | lam)] = w2[r];
    }
    __syncthreads();

    float4 u[16];
#pragma unroll
    for (int m = 0; m < 16; ++m) {
        int l0 = (lane << 1) | ((m & 1) << 7) | (((m >> 1) & 1) << 8)
               | (((m >> 2) & 1) << 9) | (((m >> 3) & 1) << 10);
        u[m] = *(float4*)&lds[swz1(l0)];
    }
    {
        const float C = c[7], SV = sv[7];
#pragma unroll
        for (int m = 0; m < 16; m += 2) {
            float4 A = u[m], B = u[m + 1];
            u[m]     = make_float4(C*A.x + SV*B.y, C*A.y - SV*B.x, C*A.z + SV*B.w, C*A.w - SV*B.z);
            u[m + 1] = make_float4(C*B.x + SV*A.y, C*B.y - SV*A.x, C*B.z + SV*A.w, C*B.w - SV*A.z);
        }
    }
#pragma unroll
    for (int m = 0; m < 16; ++m) {
        int l0 = (lane << 1) | ((m & 1) << 7) | (((m >> 1) & 1) << 8)
               | (((m >> 2) & 1) << 9) | (((m >> 3) & 1) << 10);
        *(float4*)(opp + l0) = u[m];
    }
}

__device__ __forceinline__ int ppos(int h, int q) {
    return (h << 4) + (((q ^ (h & 7) ^ ((h >> 5) & 7)) & 7) << 1);
}

__global__ __launch_bounds__(256) void rx_pass2(
        const float* __restrict__ thetas, float2* __restrict__ out) {
    __shared__ float2 buf[8192];
    const int tid = threadIdx.x;
    const int b = blockIdx.x >> 7;
    const int lb = blockIdx.x & 127;
    float2* p = out + ((size_t)b << NQ) + (lb << 4);

    float c[9], sv[9];
#pragma unroll
    for (int i = 0; i < 9; ++i) {
        float th = 0.5f * thetas[b * NQ + (8 - i)];
        c[i]  = bcast_first(cosf(th));
        sv[i] = bcast_first(sinf(th));
    }

#pragma unroll
    for (int i = 0; i < 16; ++i) {
        int f = (i << 8) | tid;
        int h = f >> 3, j = f & 7;
        float4 t = *(const float4*)(p + h * 2048 + (j << 1));
        *(float4*)&buf[ppos(h, j)] = t;
    }
    __syncthreads();

    {
        const int hl = tid & 31;
        const int j  = tid >> 5;
        float4 w[16];
#pragma unroll
        for (int m = 0; m < 16; ++m)
            w[m] = *(float4*)&buf[ppos((m << 5) | hl, j)];
#pragma unroll
        for (int t = 0; t < 4; ++t) {
            const float C = c[5 + t], SV = sv[5 + t];
            const int msk = 1 << t;
#pragma unroll
            for (int m = 0; m < 16; ++m)
                if (!(m & msk)) bfly4(C, SV, w[m], w[m | msk]);
        }
#pragma unroll
        for (int m = 0; m < 16; ++m)
            *(float4*)&buf[ppos((m << 5) | hl, j)] = w[m];
    }
    __syncthreads();

    {
        const int hh = tid >> 4;
        const int ll = tid & 15;
        float2 v[32];
#pragma unroll
        for (int r = 0; r < 32; ++r)
            v[r] = buf[ppos((hh << 5) | r, ll >> 1) + (ll & 1)];
#pragma unroll
        for (int t = 0; t < 5; ++t) {
            const float C = c[t], SV = sv[t];
            const int msk = 1 << t;
#pragma unroll
            for (int r = 0; r < 32; ++r)
                if (!(r & msk)) bfly(C, SV, v[r], v[r | msk]);
        }
#pragma unroll
        for (int r = 0; r < 32; ++r)
            p[((hh << 5) | r) * 2048 + ll] = v[r];
    }
}

extern "C" void kernel_launch(void* const* d_in, const int* in_sizes, int n_in,
                              void* d_out, int out_size, void* d_ws, size_t ws_size,
                              hipStream_t stream) {
    const float* phi    = (const float*)d_in[0];
    const float* thetas = (const float*)d_in[1];
    float2* out = (float2*)d_out;
    const size_t half_bytes = ((size_t)16 << NQ) * 4;    // 64 MiB fp16 intermediate
    const size_t need = half_bytes + 4096;               // + trig table
    if (d_ws != nullptr && ws_size >= need) {
        unsigned int* inter = (unsigned int*)d_ws;
        float2* tab = (float2*)((char*)d_ws + half_bytes);
        rx_trig<<<1, 320, 0, stream>>>(thetas, tab);
        rx_hi<<<1024, 512, 0, stream>>>(phi, tab, inter);
        rx_lo<<<1024, 512, 0, stream>>>(tab, inter, out);
    } else {
        rx_pass1<<<8192, 64, 0, stream>>>(phi, thetas, out);
        rx_pass2<<<2048, 256, 0, stream>>>(thetas, out);
    }
}

// Round 7
// 227.129 us; speedup vs baseline: 1.6172x; 1.6172x over previous
//
#include <hip/hip_runtime.h>

#define NQ 20

__device__ __forceinline__ float bcast_first(float x) {
    return __int_as_float(__builtin_amdgcn_readfirstlane(__float_as_int(x)));
}

// RX butterfly, symmetric form: new = C*mine + SV*(partner.im, -partner.re)
__device__ __forceinline__ void bfly(float C, float SV, float2& a, float2& b) {
    float2 na = make_float2(C * a.x + SV * b.y, C * a.y - SV * b.x);
    float2 nb = make_float2(C * b.x + SV * a.y, C * b.y - SV * a.x);
    a = na; b = nb;
}

// vectorized over two complex packed in float4 (same butterfly both halves)
__device__ __forceinline__ void bfly4(float C, float SV, float4& a, float4& b) {
    float4 na = make_float4(C*a.x + SV*b.y, C*a.y - SV*b.x, C*a.z + SV*b.w, C*a.w - SV*b.z);
    float4 nb = make_float4(C*b.x + SV*a.y, C*b.y - SV*a.x, C*b.z + SV*a.w, C*b.w - SV*a.z);
    a = na; b = nb;
}

// swizzled LDS index for pass1: XOR bits 2..4 by bits 7..9 of the local index
__device__ __forceinline__ int swz1(int l) { return l ^ (((l >> 7) & 7) << 2); }

// ---------------------------------------------------------------------------
// Trig table: cos/sin of thetas/2 for all B*NQ angles, computed once.
// Removes 18-22 serial libm calls from the prologue of every block
// (8192 + 2048 blocks). Proven +4us on pass2 in R4; pass1 has 4x more
// blocks at 1/4 the width, so its unhidden-prologue saving is larger.
// ---------------------------------------------------------------------------
__global__ void rx_trig(const float* __restrict__ thetas, float2* __restrict__ tab) {
    int i = threadIdx.x;
    if (i < 16 * NQ) {
        float th = 0.5f * thetas[i];
        tab[i] = make_float2(cosf(th), sinf(th));
    }
}

// ---------------------------------------------------------------------------
// Pass 1 (R0-proven structure, fp32, trig-table prologue): state-index bits
// 0..10 (qubits 19..9). One wave (=64-thread block) owns 2048 contiguous
// complex. Three register stages, two in-wave LDS exchanges. Reads real phi,
// writes complex fp32 to out (in-place buffer for pass 2).
// ---------------------------------------------------------------------------
__global__ __launch_bounds__(64) void rx_pass1t(
        const float* __restrict__ phi, const float2* __restrict__ tab,
        float2* __restrict__ out) {
    __shared__ float2 lds[2048];                    // 16 KiB
    const int lane = threadIdx.x;
    const int W = blockIdx.x;                       // [0, 8192)
    const int b = W >> 9;
    const int base = (W & 511) << 11;
    const float* ph = phi + ((size_t)b << NQ) + base;
    float2* op = out + ((size_t)b << NQ) + base;

    float c[11], sv[11];
#pragma unroll
    for (int beta = 0; beta < 11; ++beta) {
        float2 t = tab[b * NQ + (NQ - 1 - beta)];
        c[beta]  = bcast_first(t.x);
        sv[beta] = bcast_first(t.y);
    }

    float2 v[32];
#pragma unroll
    for (int k4 = 0; k4 < 8; ++k4) {
        float4 t = *(const float4*)(ph + (k4 << 8) + (lane << 2));
        v[k4 * 4 + 0] = make_float2(t.x, 0.f);
        v[k4 * 4 + 1] = make_float2(t.y, 0.f);
        v[k4 * 4 + 2] = make_float2(t.z, 0.f);
        v[k4 * 4 + 3] = make_float2(t.w, 0.f);
    }

    const int regbit1[5]  = {0, 1, 8, 9, 10};
    const int regmask1[5] = {1, 2, 4, 8, 16};
#pragma unroll
    for (int t = 0; t < 5; ++t) {
        const float C = c[regbit1[t]], SV = sv[regbit1[t]];
        const int m = regmask1[t];
#pragma unroll
        for (int r = 0; r < 32; ++r)
            if (!(r & m)) bfly(C, SV, v[r], v[r | m]);
    }

#pragma unroll
    for (int k4 = 0; k4 < 8; ++k4) {
        int low0 = (k4 << 8) + (lane << 2);
        int s0 = swz1(low0);
        *(float4*)&lds[s0]     = make_float4(v[k4*4+0].x, v[k4*4+0].y, v[k4*4+1].x, v[k4*4+1].y);
        *(float4*)&lds[s0 + 2] = make_float4(v[k4*4+2].x, v[k4*4+2].y, v[k4*4+3].x, v[k4*4+3].y);
    }
    __syncthreads();

    {
        const int g = lane >> 2, lam = lane & 3;
        float2 w2[32];
#pragma unroll
        for (int r = 0; r < 32; ++r) {
            int l = (g << 7) | (r << 2) | lam;
            w2[r] = lds[swz1(l)];
        }
#pragma unroll
        for (int t = 0; t < 5; ++t) {
            const float C = c[2 + t], SV = sv[2 + t];
            const int m = 1 << t;
#pragma unroll
            for (int r = 0; r < 32; ++r)
                if (!(r & m)) bfly(C, SV, w2[r], w2[r | m]);
        }
#pragma unroll
        for (int r = 0; r < 32; ++r) {
            int l = (g << 7) | (r << 2) | lam;
            lds[swz1(l)] = w2[r];
        }
    }
    __syncthreads();

    float4 u[16];
#pragma unroll
    for (int m = 0; m < 16; ++m) {
        int l0 = (lane << 1) | ((m & 1) << 7) | (((m >> 1) & 1) << 8)
               | (((m >> 2) & 1) << 9) | (((m >> 3) & 1) << 10);
        u[m] = *(float4*)&lds[swz1(l0)];
    }
    {
        const float C = c[7], SV = sv[7];
#pragma unroll
        for (int m = 0; m < 16; m += 2) {
            float4 A = u[m], B = u[m + 1];
            u[m]     = make_float4(C*A.x + SV*B.y, C*A.y - SV*B.x, C*A.z + SV*B.w, C*A.w - SV*B.z);
            u[m + 1] = make_float4(C*B.x + SV*A.y, C*B.y - SV*A.x, C*B.z + SV*A.w, C*B.w - SV*A.z);
        }
    }
#pragma unroll
    for (int m = 0; m < 16; ++m) {
        int l0 = (lane << 1) | ((m & 1) << 7) | (((m >> 1) & 1) << 8)
               | (((m >> 2) & 1) << 9) | (((m >> 3) & 1) << 10);
        *(float4*)(op + l0) = u[m];
    }
}

// ---------------------------------------------------------------------------
// Pass 2 (R0-proven structure, fp32 in-place, trig-table prologue): bits
// 11..19 (qubits 8..0). Block = 256 threads, tile = 512 h x 16 lows, 64 KiB
// LDS. In-place on out keeps the working set = out (L3-resident).
// ---------------------------------------------------------------------------
__device__ __forceinline__ int ppos(int h, int q) {
    return (h << 4) + (((q ^ (h & 7) ^ ((h >> 5) & 7)) & 7) << 1);
}

__global__ __launch_bounds__(256) void rx_pass2t(
        const float2* __restrict__ tab, float2* __restrict__ out) {
    __shared__ float2 buf[8192];                    // 64 KiB
    const int tid = threadIdx.x;
    const int b = blockIdx.x >> 7;
    const int lb = blockIdx.x & 127;
    float2* p = out + ((size_t)b << NQ) + (lb << 4);

    // h-bit i <-> qubit 8-i
    float c[9], sv[9];
#pragma unroll
    for (int i = 0; i < 9; ++i) {
        float2 t = tab[b * NQ + (8 - i)];
        c[i]  = bcast_first(t.x);
        sv[i] = bcast_first(t.y);
    }

    // Stage A: global -> LDS, 16 float4/thread, 128B-chunk coalesced
#pragma unroll
    for (int i = 0; i < 16; ++i) {
        int f = (i << 8) | tid;                     // [0, 4096)
        int h = f >> 3, j = f & 7;
        float4 t = *(const float4*)(p + h * 2048 + (j << 1));
        *(float4*)&buf[ppos(h, j)] = t;
    }
    __syncthreads();

    // Stage B2: h bits 5..8 (qubits 3..0), regs m in [0,16), vectorized low-pair
    {
        const int hl = tid & 31;                    // h bits 0..4
        const int j  = tid >> 5;                    // low pair [0,8)
        float4 w[16];
#pragma unroll
        for (int m = 0; m < 16; ++m)
            w[m] = *(float4*)&buf[ppos((m << 5) | hl, j)];
#pragma unroll
        for (int t = 0; t < 4; ++t) {
            const float C = c[5 + t], SV = sv[5 + t];
            const int msk = 1 << t;
#pragma unroll
            for (int m = 0; m < 16; ++m)
                if (!(m & msk)) bfly4(C, SV, w[m], w[m | msk]);
        }
#pragma unroll
        for (int m = 0; m < 16; ++m)
            *(float4*)&buf[ppos((m << 5) | hl, j)] = w[m];
    }
    __syncthreads();

    // Stage B1: h bits 0..4 (qubits 8..4), regs r in [0,32), direct global store
    {
        const int hh = tid >> 4;                    // h bits 5..8
        const int ll = tid & 15;                    // low offset
        float2 v[32];
#pragma unroll
        for (int r = 0; r < 32; ++r) {
            int h = (hh << 5) | r;
            v[r] = buf[ppos(h, ll >> 1) + (ll & 1)];
        }
#pragma unroll
        for (int t = 0; t < 5; ++t) {
            const float C = c[t], SV = sv[t];
            const int msk = 1 << t;
#pragma unroll
            for (int r = 0; r < 32; ++r)
                if (!(r & msk)) bfly(C, SV, v[r], v[r | msk]);
        }
#pragma unroll
        for (int r = 0; r < 32; ++r) {
            int h = (hh << 5) | r;
            p[h * 2048 + ll] = v[r];
        }
    }
}

// ---------------------------------------------------------------------------
// Fallback (R0 verbatim, inline trig, no ws needed).
// ---------------------------------------------------------------------------
__global__ __launch_bounds__(64) void rx_pass1(
        const float* __restrict__ phi, const float* __restrict__ thetas,
        float2* __restrict__ out) {
    __shared__ float2 lds[2048];
    const int lane = threadIdx.x;
    const int W = blockIdx.x;
    const int b = W >> 9;
    const int base = (W & 511) << 11;
    const float* ph = phi + ((size_t)b << NQ) + base;
    float2* op = out + ((size_t)b << NQ) + base;

    float c[11], sv[11];
#pragma unroll
    for (int beta = 0; beta < 11; ++beta) {
        float th = 0.5f * thetas[b * NQ + (NQ - 1 - beta)];
        c[beta]  = bcast_first(cosf(th));
        sv[beta] = bcast_first(sinf(th));
    }

    float2 v[32];
#pragma unroll
    for (int k4 = 0; k4 < 8; ++k4) {
        float4 t = *(const float4*)(ph + (k4 << 8) + (lane << 2));
        v[k4 * 4 + 0] = make_float2(t.x, 0.f);
        v[k4 * 4 + 1] = make_float2(t.y, 0.f);
        v[k4 * 4 + 2] = make_float2(t.z, 0.f);
        v[k4 * 4 + 3] = make_float2(t.w, 0.f);
    }

    const int regbit1[5]  = {0, 1, 8, 9, 10};
    const int regmask1[5] = {1, 2, 4, 8, 16};
#pragma unroll
    for (int t = 0; t < 5; ++t) {
        const float C = c[regbit1[t]], SV = sv[regbit1[t]];
        const int m = regmask1[t];
#pragma unroll
        for (int r = 0; r < 32; ++r)
            if (!(r & m)) bfly(C, SV, v[r], v[r | m]);
    }

#pragma unroll
    for (int k4 = 0; k4 < 8; ++k4) {
        int low0 = (k4 << 8) + (lane << 2);
        int s0 = swz1(low0);
        *(float4*)&lds[s0]     = make_float4(v[k4*4+0].x, v[k4*4+0].y, v[k4*4+1].x, v[k4*4+1].y);
        *(float4*)&lds[s0 + 2] = make_float4(v[k4*4+2].x, v[k4*4+2].y, v[k4*4+3].x, v[k4*4+3].y);
    }
    __syncthreads();

    {
        const int g = lane >> 2, lam = lane & 3;
        float2 w2[32];
#pragma unroll
        for (int r = 0; r < 32; ++r) {
            int l = (g << 7) | (r << 2) | lam;
            w2[r] = lds[swz1(l)];
        }
#pragma unroll
        for (int t = 0; t < 5; ++t) {
            const float C = c[2 + t], SV = sv[2 + t];
            const int m = 1 << t;
#pragma unroll
            for (int r = 0; r < 32; ++r)
                if (!(r & m)) bfly(C, SV, w2[r], w2[r | m]);
        }
#pragma unroll
        for (int r = 0; r < 32; ++r) {
            int l = (g << 7) | (r << 2) | lam;
            lds[swz1(l)] = w2[r];
        }
    }
    __syncthreads();

    float4 u[16];
#pragma unroll
    for (int m = 0; m < 16; ++m) {
        int l0 = (lane << 1) | ((m & 1) << 7) | (((m >> 1) & 1) << 8)
               | (((m >> 2) & 1) << 9) | (((m >> 3) & 1) << 10);
        u[m] = *(float4*)&lds[swz1(l0)];
    }
    {
        const float C = c[7], SV = sv[7];
#pragma unroll
        for (int m = 0; m < 16; m += 2) {
            float4 A = u[m], B = u[m + 1];
            u[m]     = make_float4(C*A.x + SV*B.y, C*A.y - SV*B.x, C*A.z + SV*B.w, C*A.w - SV*B.z);
            u[m + 1] = make_float4(C*B.x + SV*A.y, C*B.y - SV*A.x, C*B.z + SV*A.w, C*B.w - SV*A.z);
        }
    }
#pragma unroll
    for (int m = 0; m < 16; ++m) {
        int l0 = (lane << 1) | ((m & 1) << 7) | (((m >> 1) & 1) << 8)
               | (((m >> 2) & 1) << 9) | (((m >> 3) & 1) << 10);
        *(float4*)(op + l0) = u[m];
    }
}

__global__ __launch_bounds__(256) void rx_pass2(
        const float* __restrict__ thetas, float2* __restrict__ out) {
    __shared__ float2 buf[8192];
    const int tid = threadIdx.x;
    const int b = blockIdx.x >> 7;
    const int lb = blockIdx.x & 127;
    float2* p = out + ((size_t)b << NQ) + (lb << 4);

    float c[9], sv[9];
#pragma unroll
    for (int i = 0; i < 9; ++i) {
        float th = 0.5f * thetas[b * NQ + (8 - i)];
        c[i]  = bcast_first(cosf(th));
        sv[i] = bcast_first(sinf(th));
    }

#pragma unroll
    for (int i = 0; i < 16; ++i) {
        int f = (i << 8) | tid;
        int h = f >> 3, j = f & 7;
        float4 t = *(const float4*)(p + h * 2048 + (j << 1));
        *(float4*)&buf[ppos(h, j)] = t;
    }
    __syncthreads();

    {
        const int hl = tid & 31;
        const int j  = tid >> 5;
        float4 w[16];
#pragma unroll
        for (int m = 0; m < 16; ++m)
            w[m] = *(float4*)&buf[ppos((m << 5) | hl, j)];
#pragma unroll
        for (int t = 0; t < 4; ++t) {
            const float C = c[5 + t], SV = sv[5 + t];
            const int msk = 1 << t;
#pragma unroll
            for (int m = 0; m < 16; ++m)
                if (!(m & msk)) bfly4(C, SV, w[m], w[m | msk]);
        }
#pragma unroll
        for (int m = 0; m < 16; ++m)
            *(float4*)&buf[ppos((m << 5) | hl, j)] = w[m];
    }
    __syncthreads();

    {
        const int hh = tid >> 4;
        const int ll = tid & 15;
        float2 v[32];
#pragma unroll
        for (int r = 0; r < 32; ++r) {
            int h = (hh << 5) | r;
            v[r] = buf[ppos(h, ll >> 1) + (ll & 1)];
        }
#pragma unroll
        for (int t = 0; t < 5; ++t) {
            const float C = c[t], SV = sv[t];
            const int msk = 1 << t;
#pragma unroll
            for (int r = 0; r < 32; ++r)
                if (!(r & msk)) bfly(C, SV, v[r], v[r | msk]);
        }
#pragma unroll
        for (int r = 0; r < 32; ++r) {
            int h = (hh << 5) | r;
            p[h * 2048 + ll] = v[r];
        }
    }
}

extern "C" void kernel_launch(void* const* d_in, const int* in_sizes, int n_in,
                              void* d_out, int out_size, void* d_ws, size_t ws_size,
                              hipStream_t stream) {
    const float* phi    = (const float*)d_in[0];
    const float* thetas = (const float*)d_in[1];
    float2* out = (float2*)d_out;
    if (d_ws != nullptr && ws_size >= 16 * NQ * sizeof(float2)) {
        float2* tab = (float2*)d_ws;
        rx_trig<<<1, 320, 0, stream>>>(thetas, tab);
        rx_pass1t<<<8192, 64, 0, stream>>>(phi, tab, out);
        rx_pass2t<<<2048, 256, 0, stream>>>(tab, out);
    } else {
        rx_pass1<<<8192, 64, 0, stream>>>(phi, thetas, out);
        rx_pass2<<<2048, 256, 0, stream>>>(thetas, out);
    }
}